// Round 7
// baseline (193.425 us; speedup 1.0000x reference)
//
#include <hip/hip_runtime.h>
#include <hip/hip_bf16.h>

using f32x4 = __attribute__((ext_vector_type(4))) float;
using s16x8 = __attribute__((ext_vector_type(8))) short;   // 8 bf16 (4 VGPRs)

// ---------- bf16 helpers ----------
static __device__ __forceinline__ float bflo2f(unsigned int w) {
    union { unsigned int u; float f; } c; c.u = w << 16; return c.f;
}
static __device__ __forceinline__ float bfhi2f(unsigned int w) {
    union { unsigned int u; float f; } c; c.u = w & 0xffff0000u; return c.f;
}
static __device__ __forceinline__ unsigned int f2bf(float f) {
    union { float f; unsigned int u; } c; c.f = f;
    unsigned int u = c.u;
    u = u + 0x7fffu + ((u >> 16) & 1u);   // round-to-nearest-even
    return u >> 16;
}

// ======================= CSR build =======================

__global__ __launch_bounds__(256) void k_hist(
        const int* __restrict__ dst, int* __restrict__ cnt, int E)
{
    int e = blockIdx.x * 256 + threadIdx.x;
    if (e < E) atomicAdd(&cnt[dst[e]], 1);
}

// single-block scan: thread t owns contiguous chunk [t*per, t*per+per).
// off[i] = exclusive prefix of cnt. Replaces scan1+scan2+scan3 (3 launches -> 1).
__global__ __launch_bounds__(1024) void k_scan_one(
        const int* __restrict__ cnt, int* __restrict__ off, int N, int E)
{
    __shared__ int sh[1024];
    int t = threadIdx.x;
    int per = (N + 1023) >> 10;
    int i0 = t * per;
    int i1 = min(i0 + per, N);
    int s = 0;
    for (int i = i0; i < i1; ++i) s += cnt[i];
    sh[t] = s;
    __syncthreads();
    #pragma unroll
    for (int d = 1; d < 1024; d <<= 1) {
        int y = (t >= d) ? sh[t - d] : 0;
        __syncthreads();
        sh[t] += y;
        __syncthreads();
    }
    int base = sh[t] - s;                 // exclusive prefix of this chunk
    for (int i = i0; i < i1; ++i) {
        int c = cnt[i];
        off[i] = base;
        base += c;
    }
    if (t == 1023) off[N] = E;
}

// permute bumps off[d] itself: post-permute off[d] == end of segment d,
// so segment d = [ d? off[d-1] : 0 , off[d] ).
__global__ __launch_bounds__(256) void k_permute(
        const int* __restrict__ src, const int* __restrict__ dst,
        int* __restrict__ off, int* __restrict__ srcS, int E)
{
    int e = blockIdx.x * 256 + threadIdx.x;
    if (e < E) {
        int d = dst[e];
        int p = atomicAdd(&off[d], 1);
        srcS[p] = src[e];
    }
}

// ---------- convert x -> xb (bf16) + prep weight fragments + zero cnt ------
// Blocks [0,nxb): x conversion.
// Blocks [nxb, nxb+16): wprep[s] (frag-ordered weights, see k_combine_mfma).
// Blocks [nxb+16, ...): zero cnt[N].
__global__ __launch_bounds__(256) void k_convert(
        const float* __restrict__ x, unsigned short* __restrict__ xb,
        const float* __restrict__ Wr, const float* __restrict__ Wl,
        s16x8* __restrict__ wprep, int* __restrict__ cnt,
        int n4, int nxb, int N)
{
    int b = blockIdx.x;
    if (b < nxb) {
        int t = b * 256 + threadIdx.x;
        if (t >= n4) return;
        float4 v = ((const float4*)x)[t];
        ushort4 o;
        o.x = (unsigned short)f2bf(v.x);
        o.y = (unsigned short)f2bf(v.y);
        o.z = (unsigned short)f2bf(v.z);
        o.w = (unsigned short)f2bf(v.w);
        ((ushort4*)xb)[t] = o;
    } else if (b < nxb + 16) {
        int s = (b - nxb) * 256 + threadIdx.x;
        if (s >= 4096) return;
        int f = s >> 6, il = s & 63;
        int nt = f >> 3, ks = f & 7;
        int col = nt * 16 + (il & 15);
        int k   = ks * 32 + (il >> 4) * 8;
        const float* Wsrc = (k < 128) ? Wr : Wl;
        int k0 = k & 127;
        const float4* wp = (const float4*)(Wsrc + (size_t)col * 128 + k0);
        float4 w0 = wp[0], w1 = wp[1];
        s16x8 v;
        v[0] = (short)f2bf(w0.x); v[1] = (short)f2bf(w0.y);
        v[2] = (short)f2bf(w0.z); v[3] = (short)f2bf(w0.w);
        v[4] = (short)f2bf(w1.x); v[5] = (short)f2bf(w1.y);
        v[6] = (short)f2bf(w1.z); v[7] = (short)f2bf(w1.w);
        wprep[s] = v;
    } else {
        int z = (b - nxb - 16) * 256 + threadIdx.x;  // int4 index
        int base = z * 4;
        if (base + 4 <= N) {
            ((int4*)cnt)[z] = make_int4(0, 0, 0, 0);
        } else if (base < N) {
            for (int i = base; i < N; ++i) cnt[i] = 0;
        }
    }
}

// ---------- wide gather: one wave per dst node ----------
// lane = 16*r + c: slot r in [0,4) = edge in flight, c in [0,16) = 16B chunk
// (8 bf16 features) of the row. One wave load inst covers 4 rows (1KB);
// unroll 2 -> 8 edges in flight. Final shfl_xor(16,32) reduces slots;
// lanes r==0 pack bf16 and store the 256B row.
__global__ __launch_bounds__(256) void k_gather_wide(
        const uint4* __restrict__ xq, const int* __restrict__ srcS,
        const int* __restrict__ off, uint4* __restrict__ abq, int N)
{
    int d    = blockIdx.x * 4 + (threadIdx.x >> 6);
    int lane = threadIdx.x & 63;
    if (d >= N) return;
    int n1 = off[d];
    int n0 = (d > 0) ? off[d - 1] : 0;
    int c = lane & 15, r = lane >> 4;
    float a0=0,a1=0,a2=0,a3=0,a4=0,a5=0,a6=0,a7=0;
    const uint4 z4 = {0u, 0u, 0u, 0u};
    for (int p = n0; p < n1; p += 8) {
        int pe0 = p + r, pe1 = p + 4 + r;
        bool b0 = pe0 < n1, b1 = pe1 < n1;
        uint4 v0 = z4, v1 = z4;
        if (b0) v0 = xq[(size_t)srcS[pe0] * 16 + c];
        if (b1) v1 = xq[(size_t)srcS[pe1] * 16 + c];
        a0 += bflo2f(v0.x); a1 += bfhi2f(v0.x);
        a2 += bflo2f(v0.y); a3 += bfhi2f(v0.y);
        a4 += bflo2f(v0.z); a5 += bfhi2f(v0.z);
        a6 += bflo2f(v0.w); a7 += bfhi2f(v0.w);
        a0 += bflo2f(v1.x); a1 += bfhi2f(v1.x);
        a2 += bflo2f(v1.y); a3 += bfhi2f(v1.y);
        a4 += bflo2f(v1.z); a5 += bfhi2f(v1.z);
        a6 += bflo2f(v1.w); a7 += bfhi2f(v1.w);
    }
    // reduce across the 4 slots (lane bits 4,5)
    a0 += __shfl_xor(a0, 16, 64); a0 += __shfl_xor(a0, 32, 64);
    a1 += __shfl_xor(a1, 16, 64); a1 += __shfl_xor(a1, 32, 64);
    a2 += __shfl_xor(a2, 16, 64); a2 += __shfl_xor(a2, 32, 64);
    a3 += __shfl_xor(a3, 16, 64); a3 += __shfl_xor(a3, 32, 64);
    a4 += __shfl_xor(a4, 16, 64); a4 += __shfl_xor(a4, 32, 64);
    a5 += __shfl_xor(a5, 16, 64); a5 += __shfl_xor(a5, 32, 64);
    a6 += __shfl_xor(a6, 16, 64); a6 += __shfl_xor(a6, 32, 64);
    a7 += __shfl_xor(a7, 16, 64); a7 += __shfl_xor(a7, 32, 64);
    if (r == 0) {
        float inv = 1.0f / (float)max(n1 - n0, 1);
        uint4 o;
        o.x = f2bf(a0 * inv) | (f2bf(a1 * inv) << 16);
        o.y = f2bf(a2 * inv) | (f2bf(a3 * inv) << 16);
        o.z = f2bf(a4 * inv) | (f2bf(a5 * inv) << 16);
        o.w = f2bf(a6 * inv) | (f2bf(a7 * inv) << 16);
        abq[(size_t)d * 16 + c] = o;
    }
}

// ---------- MFMA combine: out = [xb|ab] @ [Wr|Wl]^T + bl ----------
// B fragments in LDS (64 KiB), copied from wprep.
// Per wave: 16 rows x 128 cols; A-frag row = lane&15, k-slice = (lane>>4)*8.
// D layout (m89): row = (lane>>4)*4 + i, col = lane&15.
__global__ __launch_bounds__(256) void k_combine_mfma(
        const unsigned short* __restrict__ xb, const unsigned short* __restrict__ ab,
        const s16x8* __restrict__ wprep,
        const float* __restrict__ bl,
        float* __restrict__ out, int N, int T)
{
    __shared__ s16x8 Bf[64][64];                  // 65536 B
    int t = threadIdx.x;
    {
        const uint4* ws = (const uint4*)wprep;
        uint4* bd = (uint4*)&Bf[0][0];
        for (int s = t; s < 4096; s += 256) bd[s] = ws[s];
    }
    __syncthreads();

    int wid = t >> 6, l = t & 63;
    int lr = l & 15, lg = l >> 4;
    float bias[8];
    #pragma unroll
    for (int nt = 0; nt < 8; ++nt) bias[nt] = bl[nt * 16 + lr];

    for (int tile = blockIdx.x; tile < T; tile += gridDim.x) {
        int rowbase = tile * 64 + wid * 16;
        int arow = min(rowbase + lr, N - 1);      // clamp for tail tile
        const s16x8* xr = (const s16x8*)(xb + (size_t)arow * 128);
        const s16x8* ar = (const s16x8*)(ab + (size_t)arow * 128);
        s16x8 af[8];
        #pragma unroll
        for (int ks = 0; ks < 4; ++ks) af[ks]     = xr[ks * 4 + lg];
        #pragma unroll
        for (int ks = 0; ks < 4; ++ks) af[4 + ks] = ar[ks * 4 + lg];

        f32x4 acc[8];
        #pragma unroll
        for (int nt = 0; nt < 8; ++nt) {
            float b = bias[nt];
            acc[nt] = (f32x4){b, b, b, b};
        }

        #pragma unroll
        for (int ks = 0; ks < 8; ++ks)
            #pragma unroll
            for (int nt = 0; nt < 8; ++nt)
                acc[nt] = __builtin_amdgcn_mfma_f32_16x16x32_bf16(
                              af[ks], Bf[nt * 8 + ks][l], acc[nt], 0, 0, 0);

        #pragma unroll
        for (int i = 0; i < 4; ++i) {
            int row = rowbase + lg * 4 + i;
            if (row < N) {
                float* op = out + (size_t)row * 128 + lr;
                #pragma unroll
                for (int nt = 0; nt < 8; ++nt) op[nt * 16] = acc[nt][i];
            }
        }
    }
}

// ======================= legacy fallback (tiny ws) =======================

__global__ __launch_bounds__(256) void k_scatter_legacy(
        const float* __restrict__ x,
        const int* __restrict__ src, const int* __restrict__ dst,
        float* __restrict__ agg, float* __restrict__ deg, int E)
{
    int e    = (int)((blockIdx.x * 256u + threadIdx.x) >> 6);
    int lane = threadIdx.x & 63;
    if (e >= E) return;
    int s = src[e];
    int d = dst[e];
    float2 v = ((const float2*)(x + (size_t)s * 128u))[lane];
    float* ar = agg + (size_t)d * 128u;
    unsafeAtomicAdd(ar + 2 * lane,     v.x);
    unsafeAtomicAdd(ar + 2 * lane + 1, v.y);
    if (lane == 0) unsafeAtomicAdd(deg + d, 1.0f);
}

__global__ __launch_bounds__(256) void k_combine_legacy(
        const float* __restrict__ x, const float* agg, const float* __restrict__ deg,
        const float* __restrict__ Wr, const float* __restrict__ Wl,
        const float* __restrict__ bl,
        float* out, int N)
{
    __shared__ uint4 WT4[64][64];
    for (int idx = threadIdx.x; idx < 64 * 64; idx += 256) {
        int g = idx >> 6, l = idx & 63;
        uint4 wv;
        unsigned int* wp = &wv.x;
        #pragma unroll
        for (int kk = 0; kk < 4; ++kk) {
            int k = g * 4 + kk;
            const float* Wsrc = (k < 128) ? Wr : Wl;
            int km = k & 127;
            unsigned int lo = f2bf(Wsrc[(size_t)l * 128 + km]);
            unsigned int hi = f2bf(Wsrc[(size_t)(l + 64) * 128 + km]);
            wp[kk] = lo | (hi << 16);
        }
        WT4[g][l] = wv;
    }
    __syncthreads();

    int wid = threadIdx.x >> 6, lane = threadIdx.x & 63;
    float b0 = bl[lane], b1 = bl[lane + 64];
    for (int row = blockIdx.x * 4 + wid; row < N; row += gridDim.x * 4) {
        const float4* xr = (const float4*)(x   + (size_t)row * 128);
        const float4* ar = (const float4*)(agg + (size_t)row * 128);
        float inv = 1.0f / fmaxf(deg[row], 1.0f);
        float acc0 = b0, acc1 = b1;
        #pragma unroll 8
        for (int c = 0; c < 32; ++c) {
            uint4 w4 = WT4[c][lane];
            float4 q = xr[c];
            #pragma unroll
            for (int j = 0; j < 4; ++j) {
                unsigned int w = (&w4.x)[j];
                float f = (&q.x)[j];
                acc0 = fmaf(f, bflo2f(w), acc0);
                acc1 = fmaf(f, bfhi2f(w), acc1);
            }
        }
        #pragma unroll 8
        for (int c = 0; c < 32; ++c) {
            uint4 w4 = WT4[c + 32][lane];
            float4 q = ar[c];
            #pragma unroll
            for (int j = 0; j < 4; ++j) {
                unsigned int w = (&w4.x)[j];
                float f = (&q.x)[j] * inv;
                acc0 = fmaf(f, bflo2f(w), acc0);
                acc1 = fmaf(f, bfhi2f(w), acc1);
            }
        }
        out[(size_t)row * 128 + lane]      = acc0;
        out[(size_t)row * 128 + lane + 64] = acc1;
    }
}

// ======================= launch =======================

extern "C" void kernel_launch(void* const* d_in, const int* in_sizes, int n_in,
                              void* d_out, int out_size, void* d_ws, size_t ws_size,
                              hipStream_t stream)
{
    const float* x  = (const float*)d_in[0];
    const int*   ei = (const int*)d_in[1];
    const float* Wl = (const float*)d_in[2];
    const float* bl = (const float*)d_in[3];
    const float* Wr = (const float*)d_in[4];
    float*      out = (float*)d_out;

    int N = in_sizes[0] / 128;
    int E = in_sizes[1] / 2;
    const int* src = ei;          // edge_index[0] = source nodes (j)
    const int* dst = ei + E;      // edge_index[1] = destination nodes (i)

    size_t bfB = (size_t)N * 128 * 2;              // bf16 row block

    // ws: cnt[N] off[N+1] srcS[E] | xb | ab | wprep(64KB)
    size_t nInts = (size_t)N * 2 + 1 + (size_t)E;
    size_t intsB = ((nInts * 4) + 255) & ~(size_t)255;

    if (ws_size >= intsB + 2 * bfB + 65536) {
        // -------- MFMA path --------
        int* cnt  = (int*)d_ws;
        int* off  = cnt + N;
        int* srcS = off + N + 1;
        unsigned short* xb = (unsigned short*)((char*)d_ws + intsB);
        unsigned short* ab = xb + (size_t)N * 128;
        s16x8* wprep = (s16x8*)((char*)ab + bfB);

        int nxb = (N * 32 + 255) / 256;
        int nzb = ((N + 3) / 4 + 255) / 256;
        int ncv = nxb + 16 + nzb;                  // convert | wprep | zero-cnt

        k_convert   <<<ncv, 256, 0, stream>>>(x, xb, Wr, Wl, wprep, cnt, N * 32, nxb, N);
        k_hist      <<<(E + 255) / 256, 256, 0, stream>>>(dst, cnt, E);
        k_scan_one  <<<1, 1024, 0, stream>>>(cnt, off, N, E);
        k_permute   <<<(E + 255) / 256, 256, 0, stream>>>(src, dst, off, srcS, E);
        k_gather_wide<<<(N + 3) / 4, 256, 0, stream>>>(
                (const uint4*)xb, srcS, off, (uint4*)ab, N);
        int T = (N + 63) / 64;
        k_combine_mfma<<<512, 256, 0, stream>>>(xb, ab, wprep, bl, out, N, T);
    } else {
        // -------- legacy atomic path (agg = out, deg in ws) --------
        float* agg = out;
        float* deg = (float*)d_ws;
        hipMemsetAsync(out, 0, (size_t)N * 128 * 4, stream);
        hipMemsetAsync(deg, 0, (size_t)N * 4, stream);
        k_scatter_legacy<<<(E + 3) / 4, 256, 0, stream>>>(x, src, dst, agg, deg, E);
        k_combine_legacy<<<1024, 256, 0, stream>>>(x, agg, deg, Wr, Wl, bl, out, N);
    }
}

// Round 8
// 126.531 us; speedup vs baseline: 1.5287x; 1.5287x over previous
//
#include <hip/hip_runtime.h>
#include <hip/hip_bf16.h>

using f32x4 = __attribute__((ext_vector_type(4))) float;
using s16x8 = __attribute__((ext_vector_type(8))) short;   // 8 bf16 (4 VGPRs)

// ---------- bf16 helpers ----------
static __device__ __forceinline__ float bflo2f(unsigned int w) {
    union { unsigned int u; float f; } c; c.u = w << 16; return c.f;
}
static __device__ __forceinline__ float bfhi2f(unsigned int w) {
    union { unsigned int u; float f; } c; c.u = w & 0xffff0000u; return c.f;
}
static __device__ __forceinline__ unsigned int f2bf(float f) {
    union { float f; unsigned int u; } c; c.f = f;
    unsigned int u = c.u;
    u = u + 0x7fffu + ((u >> 16) & 1u);   // round-to-nearest-even
    return u >> 16;
}

// ======================= CSR build =======================

__global__ __launch_bounds__(256) void k_hist(
        const int* __restrict__ dst, int* __restrict__ cnt, int E)
{
    int e = blockIdx.x * 256 + threadIdx.x;
    if (e < E) atomicAdd(&cnt[dst[e]], 1);
}

// hierarchical 3-kernel scan (parallel across all CUs; the single-block
// fused version measured 76us @ 0.15% occupancy -- reverted, round 7).
__global__ __launch_bounds__(1024) void k_scan1(
        const int* __restrict__ cnt, int* __restrict__ off,
        int* __restrict__ bsum, int N)
{
    __shared__ int sh[1024];
    int t = threadIdx.x;
    int i = blockIdx.x * 1024 + t;
    int v = (i < N) ? cnt[i] : 0;
    sh[t] = v;
    __syncthreads();
    #pragma unroll
    for (int d = 1; d < 1024; d <<= 1) {
        int y = (t >= d) ? sh[t - d] : 0;
        __syncthreads();
        sh[t] += y;
        __syncthreads();
    }
    int incl = sh[t];
    if (i < N) off[i] = incl - v;                 // block-local exclusive
    if (t == 1023) bsum[blockIdx.x] = incl;
}

__global__ __launch_bounds__(1024) void k_scan2(
        const int* __restrict__ bsum, int* __restrict__ boff,
        int* __restrict__ off, int nb, int N, int E)
{
    __shared__ int sh[1024];
    int t = threadIdx.x;
    int v = (t < nb) ? bsum[t] : 0;
    sh[t] = v;
    __syncthreads();
    #pragma unroll
    for (int d = 1; d < 1024; d <<= 1) {
        int y = (t >= d) ? sh[t - d] : 0;
        __syncthreads();
        sh[t] += y;
        __syncthreads();
    }
    if (t < nb) boff[t] = sh[t] - v;
    if (t == 0) off[N] = E;
}

__global__ __launch_bounds__(1024) void k_scan3(
        int* __restrict__ off, const int* __restrict__ boff, int N)
{
    int i = blockIdx.x * 1024 + threadIdx.x;
    if (i < N) off[i] += boff[blockIdx.x];
}

// permute bumps off[d] itself: post-permute off[d] == end of segment d,
// so segment d = [ d? off[d-1] : 0 , off[d] ).
__global__ __launch_bounds__(256) void k_permute(
        const int* __restrict__ src, const int* __restrict__ dst,
        int* __restrict__ off, int* __restrict__ srcS, int E)
{
    int e = blockIdx.x * 256 + threadIdx.x;
    if (e < E) {
        int d = dst[e];
        int p = atomicAdd(&off[d], 1);
        srcS[p] = src[e];
    }
}

// ---------- convert x -> xb (bf16) + prep weight fragments + zero cnt ------
// Blocks [0,nxb): x conversion.
// Blocks [nxb, nxb+16): wprep[s] (frag-ordered weights, see k_combine_mfma).
// Blocks [nxb+16, ...): zero cnt[N].
__global__ __launch_bounds__(256) void k_convert(
        const float* __restrict__ x, unsigned short* __restrict__ xb,
        const float* __restrict__ Wr, const float* __restrict__ Wl,
        s16x8* __restrict__ wprep, int* __restrict__ cnt,
        int n4, int nxb, int N)
{
    int b = blockIdx.x;
    if (b < nxb) {
        int t = b * 256 + threadIdx.x;
        if (t >= n4) return;
        float4 v = ((const float4*)x)[t];
        ushort4 o;
        o.x = (unsigned short)f2bf(v.x);
        o.y = (unsigned short)f2bf(v.y);
        o.z = (unsigned short)f2bf(v.z);
        o.w = (unsigned short)f2bf(v.w);
        ((ushort4*)xb)[t] = o;
    } else if (b < nxb + 16) {
        int s = (b - nxb) * 256 + threadIdx.x;
        if (s >= 4096) return;
        int f = s >> 6, il = s & 63;
        int nt = f >> 3, ks = f & 7;
        int col = nt * 16 + (il & 15);
        int k   = ks * 32 + (il >> 4) * 8;
        const float* Wsrc = (k < 128) ? Wr : Wl;
        int k0 = k & 127;
        const float4* wp = (const float4*)(Wsrc + (size_t)col * 128 + k0);
        float4 w0 = wp[0], w1 = wp[1];
        s16x8 v;
        v[0] = (short)f2bf(w0.x); v[1] = (short)f2bf(w0.y);
        v[2] = (short)f2bf(w0.z); v[3] = (short)f2bf(w0.w);
        v[4] = (short)f2bf(w1.x); v[5] = (short)f2bf(w1.y);
        v[6] = (short)f2bf(w1.z); v[7] = (short)f2bf(w1.w);
        wprep[s] = v;
    } else {
        int z = (b - nxb - 16) * 256 + threadIdx.x;  // int4 index
        int base = z * 4;
        if (base + 4 <= N) {
            ((int4*)cnt)[z] = make_int4(0, 0, 0, 0);
        } else if (base < N) {
            for (int i = base; i < N; ++i) cnt[i] = 0;
        }
    }
}

// ---------- wide gather: one wave per dst node ----------
// lane = 16*r + c: slot r in [0,4) = edge in flight, c in [0,16) = 16B chunk
// (8 bf16 features) of the row. One wave load inst covers 4 rows (1KB);
// unroll 2 -> 8 edges in flight. Final shfl_xor(16,32) reduces slots;
// lanes r==0 pack bf16 and store the 256B row.
__global__ __launch_bounds__(256) void k_gather_wide(
        const uint4* __restrict__ xq, const int* __restrict__ srcS,
        const int* __restrict__ off, uint4* __restrict__ abq, int N)
{
    int d    = blockIdx.x * 4 + (threadIdx.x >> 6);
    int lane = threadIdx.x & 63;
    if (d >= N) return;
    int n1 = off[d];
    int n0 = (d > 0) ? off[d - 1] : 0;
    int c = lane & 15, r = lane >> 4;
    float a0=0,a1=0,a2=0,a3=0,a4=0,a5=0,a6=0,a7=0;
    const uint4 z4 = {0u, 0u, 0u, 0u};
    for (int p = n0; p < n1; p += 8) {
        int pe0 = p + r, pe1 = p + 4 + r;
        bool b0 = pe0 < n1, b1 = pe1 < n1;
        uint4 v0 = z4, v1 = z4;
        if (b0) v0 = xq[(size_t)srcS[pe0] * 16 + c];
        if (b1) v1 = xq[(size_t)srcS[pe1] * 16 + c];
        a0 += bflo2f(v0.x); a1 += bfhi2f(v0.x);
        a2 += bflo2f(v0.y); a3 += bfhi2f(v0.y);
        a4 += bflo2f(v0.z); a5 += bfhi2f(v0.z);
        a6 += bflo2f(v0.w); a7 += bfhi2f(v0.w);
        a0 += bflo2f(v1.x); a1 += bfhi2f(v1.x);
        a2 += bflo2f(v1.y); a3 += bfhi2f(v1.y);
        a4 += bflo2f(v1.z); a5 += bfhi2f(v1.z);
        a6 += bflo2f(v1.w); a7 += bfhi2f(v1.w);
    }
    // reduce across the 4 slots (lane bits 4,5)
    a0 += __shfl_xor(a0, 16, 64); a0 += __shfl_xor(a0, 32, 64);
    a1 += __shfl_xor(a1, 16, 64); a1 += __shfl_xor(a1, 32, 64);
    a2 += __shfl_xor(a2, 16, 64); a2 += __shfl_xor(a2, 32, 64);
    a3 += __shfl_xor(a3, 16, 64); a3 += __shfl_xor(a3, 32, 64);
    a4 += __shfl_xor(a4, 16, 64); a4 += __shfl_xor(a4, 32, 64);
    a5 += __shfl_xor(a5, 16, 64); a5 += __shfl_xor(a5, 32, 64);
    a6 += __shfl_xor(a6, 16, 64); a6 += __shfl_xor(a6, 32, 64);
    a7 += __shfl_xor(a7, 16, 64); a7 += __shfl_xor(a7, 32, 64);
    if (r == 0) {
        float inv = 1.0f / (float)max(n1 - n0, 1);
        uint4 o;
        o.x = f2bf(a0 * inv) | (f2bf(a1 * inv) << 16);
        o.y = f2bf(a2 * inv) | (f2bf(a3 * inv) << 16);
        o.z = f2bf(a4 * inv) | (f2bf(a5 * inv) << 16);
        o.w = f2bf(a6 * inv) | (f2bf(a7 * inv) << 16);
        abq[(size_t)d * 16 + c] = o;
    }
}

// ---------- MFMA combine: out = [xb|ab] @ [Wr|Wl]^T + bl ----------
// B fragments in LDS (64 KiB), copied from wprep.
// Per wave: 16 rows x 128 cols; A-frag row = lane&15, k-slice = (lane>>4)*8.
// D layout (m89): row = (lane>>4)*4 + i, col = lane&15.
__global__ __launch_bounds__(256) void k_combine_mfma(
        const unsigned short* __restrict__ xb, const unsigned short* __restrict__ ab,
        const s16x8* __restrict__ wprep,
        const float* __restrict__ bl,
        float* __restrict__ out, int N, int T)
{
    __shared__ s16x8 Bf[64][64];                  // 65536 B
    int t = threadIdx.x;
    {
        const uint4* ws = (const uint4*)wprep;
        uint4* bd = (uint4*)&Bf[0][0];
        for (int s = t; s < 4096; s += 256) bd[s] = ws[s];
    }
    __syncthreads();

    int wid = t >> 6, l = t & 63;
    int lr = l & 15, lg = l >> 4;
    float bias[8];
    #pragma unroll
    for (int nt = 0; nt < 8; ++nt) bias[nt] = bl[nt * 16 + lr];

    for (int tile = blockIdx.x; tile < T; tile += gridDim.x) {
        int rowbase = tile * 64 + wid * 16;
        int arow = min(rowbase + lr, N - 1);      // clamp for tail tile
        const s16x8* xr = (const s16x8*)(xb + (size_t)arow * 128);
        const s16x8* ar = (const s16x8*)(ab + (size_t)arow * 128);
        s16x8 af[8];
        #pragma unroll
        for (int ks = 0; ks < 4; ++ks) af[ks]     = xr[ks * 4 + lg];
        #pragma unroll
        for (int ks = 0; ks < 4; ++ks) af[4 + ks] = ar[ks * 4 + lg];

        f32x4 acc[8];
        #pragma unroll
        for (int nt = 0; nt < 8; ++nt) {
            float b = bias[nt];
            acc[nt] = (f32x4){b, b, b, b};
        }

        #pragma unroll
        for (int ks = 0; ks < 8; ++ks)
            #pragma unroll
            for (int nt = 0; nt < 8; ++nt)
                acc[nt] = __builtin_amdgcn_mfma_f32_16x16x32_bf16(
                              af[ks], Bf[nt * 8 + ks][l], acc[nt], 0, 0, 0);

        #pragma unroll
        for (int i = 0; i < 4; ++i) {
            int row = rowbase + lg * 4 + i;
            if (row < N) {
                float* op = out + (size_t)row * 128 + lr;
                #pragma unroll
                for (int nt = 0; nt < 8; ++nt) op[nt * 16] = acc[nt][i];
            }
        }
    }
}

// ======================= legacy fallback (tiny ws) =======================

__global__ __launch_bounds__(256) void k_scatter_legacy(
        const float* __restrict__ x,
        const int* __restrict__ src, const int* __restrict__ dst,
        float* __restrict__ agg, float* __restrict__ deg, int E)
{
    int e    = (int)((blockIdx.x * 256u + threadIdx.x) >> 6);
    int lane = threadIdx.x & 63;
    if (e >= E) return;
    int s = src[e];
    int d = dst[e];
    float2 v = ((const float2*)(x + (size_t)s * 128u))[lane];
    float* ar = agg + (size_t)d * 128u;
    unsafeAtomicAdd(ar + 2 * lane,     v.x);
    unsafeAtomicAdd(ar + 2 * lane + 1, v.y);
    if (lane == 0) unsafeAtomicAdd(deg + d, 1.0f);
}

__global__ __launch_bounds__(256) void k_combine_legacy(
        const float* __restrict__ x, const float* agg, const float* __restrict__ deg,
        const float* __restrict__ Wr, const float* __restrict__ Wl,
        const float* __restrict__ bl,
        float* out, int N)
{
    __shared__ uint4 WT4[64][64];
    for (int idx = threadIdx.x; idx < 64 * 64; idx += 256) {
        int g = idx >> 6, l = idx & 63;
        uint4 wv;
        unsigned int* wp = &wv.x;
        #pragma unroll
        for (int kk = 0; kk < 4; ++kk) {
            int k = g * 4 + kk;
            const float* Wsrc = (k < 128) ? Wr : Wl;
            int km = k & 127;
            unsigned int lo = f2bf(Wsrc[(size_t)l * 128 + km]);
            unsigned int hi = f2bf(Wsrc[(size_t)(l + 64) * 128 + km]);
            wp[kk] = lo | (hi << 16);
        }
        WT4[g][l] = wv;
    }
    __syncthreads();

    int wid = threadIdx.x >> 6, lane = threadIdx.x & 63;
    float b0 = bl[lane], b1 = bl[lane + 64];
    for (int row = blockIdx.x * 4 + wid; row < N; row += gridDim.x * 4) {
        const float4* xr = (const float4*)(x   + (size_t)row * 128);
        const float4* ar = (const float4*)(agg + (size_t)row * 128);
        float inv = 1.0f / fmaxf(deg[row], 1.0f);
        float acc0 = b0, acc1 = b1;
        #pragma unroll 8
        for (int c = 0; c < 32; ++c) {
            uint4 w4 = WT4[c][lane];
            float4 q = xr[c];
            #pragma unroll
            for (int j = 0; j < 4; ++j) {
                unsigned int w = (&w4.x)[j];
                float f = (&q.x)[j];
                acc0 = fmaf(f, bflo2f(w), acc0);
                acc1 = fmaf(f, bfhi2f(w), acc1);
            }
        }
        #pragma unroll 8
        for (int c = 0; c < 32; ++c) {
            uint4 w4 = WT4[c + 32][lane];
            float4 q = ar[c];
            #pragma unroll
            for (int j = 0; j < 4; ++j) {
                unsigned int w = (&w4.x)[j];
                float f = (&q.x)[j] * inv;
                acc0 = fmaf(f, bflo2f(w), acc0);
                acc1 = fmaf(f, bfhi2f(w), acc1);
            }
        }
        out[(size_t)row * 128 + lane]      = acc0;
        out[(size_t)row * 128 + lane + 64] = acc1;
    }
}

// ======================= launch =======================

extern "C" void kernel_launch(void* const* d_in, const int* in_sizes, int n_in,
                              void* d_out, int out_size, void* d_ws, size_t ws_size,
                              hipStream_t stream)
{
    const float* x  = (const float*)d_in[0];
    const int*   ei = (const int*)d_in[1];
    const float* Wl = (const float*)d_in[2];
    const float* bl = (const float*)d_in[3];
    const float* Wr = (const float*)d_in[4];
    float*      out = (float*)d_out;

    int N = in_sizes[0] / 128;
    int E = in_sizes[1] / 2;
    const int* src = ei;          // edge_index[0] = source nodes (j)
    const int* dst = ei + E;      // edge_index[1] = destination nodes (i)

    int nb = (N + 1023) / 1024;
    size_t bfB = (size_t)N * 128 * 2;              // bf16 row block

    // ws: cnt[N] off[N+1] bsum[nb] boff[nb] srcS[E] | xb | ab | wprep(64KB)
    size_t nInts = (size_t)N * 2 + 1 + 2 * (size_t)nb + (size_t)E;
    size_t intsB = ((nInts * 4) + 255) & ~(size_t)255;

    if (ws_size >= intsB + 2 * bfB + 65536 && nb <= 1024) {
        // -------- MFMA path --------
        int* cnt  = (int*)d_ws;
        int* off  = cnt + N;
        int* bsum = off + N + 1;
        int* boff = bsum + nb;
        int* srcS = boff + nb;
        unsigned short* xb = (unsigned short*)((char*)d_ws + intsB);
        unsigned short* ab = xb + (size_t)N * 128;
        s16x8* wprep = (s16x8*)((char*)ab + bfB);

        int nxb = (N * 32 + 255) / 256;
        int nzb = ((N + 3) / 4 + 255) / 256;
        int ncv = nxb + 16 + nzb;                  // convert | wprep | zero-cnt

        k_convert   <<<ncv, 256, 0, stream>>>(x, xb, Wr, Wl, wprep, cnt, N * 32, nxb, N);
        k_hist      <<<(E + 255) / 256, 256, 0, stream>>>(dst, cnt, E);
        k_scan1     <<<nb, 1024, 0, stream>>>(cnt, off, bsum, N);
        k_scan2     <<<1,  1024, 0, stream>>>(bsum, boff, off, nb, N, E);
        k_scan3     <<<nb, 1024, 0, stream>>>(off, boff, N);
        k_permute   <<<(E + 255) / 256, 256, 0, stream>>>(src, dst, off, srcS, E);
        k_gather_wide<<<(N + 3) / 4, 256, 0, stream>>>(
                (const uint4*)xb, srcS, off, (uint4*)ab, N);
        int T = (N + 63) / 64;
        k_combine_mfma<<<512, 256, 0, stream>>>(xb, ab, wprep, bl, out, N, T);
    } else {
        // -------- legacy atomic path (agg = out, deg in ws) --------
        float* agg = out;
        float* deg = (float*)d_ws;
        hipMemsetAsync(out, 0, (size_t)N * 128 * 4, stream);
        hipMemsetAsync(deg, 0, (size_t)N * 4, stream);
        k_scatter_legacy<<<(E + 3) / 4, 256, 0, stream>>>(x, src, dst, agg, deg, E);
        k_combine_legacy<<<1024, 256, 0, stream>>>(x, agg, deg, Wr, Wl, bl, out, N);
    }
}